// Round 17
// baseline (98.669 us; speedup 1.0000x reference)
//
#include <hip/hip_runtime.h>

#define NB    16
#define CIN   64
#define TT    512
#define VV    22
#define COUT  256
#define TBK   4            // t per block/tile
#define NTB   (TT / TBK)   // 128
#define ZROW  (TBK * VV)   // 88
#define PAD   24           // fallback kernel pads
#define OPAD  23

typedef __attribute__((ext_vector_type(8))) short bf16x8;
typedef __attribute__((ext_vector_type(4))) float f32x4;

__device__ __forceinline__ ushort f2bf(float f) {   // RNE fp32 -> bf16
    unsigned u = __float_as_uint(f);
    return (ushort)((u + 0x7FFFu + ((u >> 16) & 1u)) >> 16);
}
__device__ __forceinline__ uint pk2(float a, float b) {
    return (uint)f2bf(a) | ((uint)f2bf(b) << 16);
}

// ===================== Prep: Wa/Wb/Wd -> bf16 (once, into ws) =====================
__global__ void w_to_bf16(const float* __restrict__ Wa, const float* __restrict__ Wb,
                          const float* __restrict__ Wd,
                          ushort* __restrict__ WaB, ushort* __restrict__ WbB,
                          ushort* __restrict__ WdB)
{
    int i = blockIdx.x * 256 + threadIdx.x;
    if (i < CIN * CIN)                 WaB[i] = f2bf(Wa[i]);
    else if (i < 2 * CIN * CIN)        WbB[i - CIN * CIN] = f2bf(Wb[i - CIN * CIN]);
    else if (i < 2 * CIN * CIN + COUT * CIN)
                                       WdB[i - 2 * CIN * CIN] = f2bf(Wd[i - 2 * CIN * CIN]);
}

// ===================== Fused kernel (R16 structure, LDS trimmed to 38912B -> 4 blocks/CU) =====
// Per block (tq, n): 4 t's end-to-end; z never leaves LDS.
// Fragment conventions (HW-validated R12/R13):
//   A-op: lane l holds A[row = tile*16 + (l&15)][k = kb*32 + (l>>4)*8 + j]
//   B-op: lane l holds B[k][col = tile*16 + (l&15)],  C/D: col = l&15, row = (l>>4)*4 + reg
__global__ __launch_bounds__(256, 4) void agcn_fused_mfma(
    const float* __restrict__ x, const float* __restrict__ A,
    const ushort* __restrict__ WaB, const float* __restrict__ ba,
    const ushort* __restrict__ WbB, const float* __restrict__ bb,
    const ushort* __restrict__ WdB, const float* __restrict__ bd,
    float* __restrict__ out)
{
    const int bx = blockIdx.x;                   // 0..127
    const int tq = (bx & 7) * 16 + (bx >> 3);    // XCD swizzle
    const int n  = blockIdx.y;
    const int tid = threadIdx.x;
    const int lane = tid & 63, wave = tid >> 6;
    const int hi = lane >> 4, lo = lane & 15;
    const int t0 = tq * TBK;

    // LDS 38912B total: xsb 16384 | frag 22528.
    // frag timeline: xbf(16384) -> A1bf+A2bf(22528) -> z_lds(12288) + psb(5632 @ +12288)
    __shared__ __align__(16) ushort xsb[TBK * 64 * 32];   // [t][c][w<32]; zbf overlays in phase B
    __shared__ __align__(16) ushort frag[11264];
    ushort* xbf   = frag;            // P1 B-frags [kb2][t4][nt2][ln64][8] = 8192 us
    ushort* A1bf  = frag;            // [t][u<22][i<64] = 5632 us
    ushort* A2bf  = frag + 5632;
    ushort* z_lds = frag;            // bf16 [c<64][96] = 6144 us (post-P2)
    ushort* psb   = frag + 6144;     // [t][u<22][w<32] = 2816 us (post-P2, wave-private per t)
    ushort* zbf   = xsb;             // [kb2][nt6][ln64][8] = 6144 us (phase B)

    // ---- zero xsb pads (cols 22..31) ----
    for (int i = tid; i < TBK * 64 * 5; i += 256) {
        int row = i / 5, q = i - row * 5;
        reinterpret_cast<uint*>(&xsb[row * 32 + 22])[q] = 0u;
    }

    // ---- P0: stage x (352B-contiguous per c) -> bf16 LDS ----
    {
        const float* xsrc = x + ((size_t)n * CIN * TT + t0) * VV;
        for (int i4 = tid; i4 < CIN * 22; i4 += 256) {
            int c = i4 / 22, q = i4 - c * 22;
            float4 v4 = *reinterpret_cast<const float4*>(xsrc + (size_t)c * (TT * VV) + q * 4);
            #pragma unroll
            for (int j = 0; j < 4; ++j) {
                int e  = q * 4 + j;
                int tt = e / 22, v = e - tt * 22;
                float val = (j == 0) ? v4.x : (j == 1) ? v4.y : (j == 2) ? v4.z : v4.w;
                xsb[(tt * 64 + c) * 32 + v] = f2bf(val);
            }
        }
    }
    __syncthreads();

    // ---- conv1: P1 B-frags from xsb ----
    for (int it = tid; it < 1024; it += 256) {
        int kb = it >> 9;
        int t  = (it >> 7) & 3;
        int nt = (it >> 6) & 1;
        int ln = it & 63;
        int v  = nt * 16 + (ln & 15);
        int c0 = kb * 32 + (ln >> 4) * 8;
        ushort tmp[8];
        #pragma unroll
        for (int j = 0; j < 8; ++j) tmp[j] = xsb[(t * 64 + c0 + j) * 32 + v];
        *reinterpret_cast<uint4*>(&xbf[(size_t)it * 8]) = *reinterpret_cast<const uint4*>(tmp);
    }
    __syncthreads();

    // ---- P1 MFMA: A1 = Wa@X+ba, A2 = Wb@X+bb for all 4 t's ----
    f32x4 acc_a[TBK][2], acc_b[TBK][2];
    {
        const int m0 = wave * 16;
        float bav[4], bbv[4];
        #pragma unroll
        for (int r = 0; r < 4; ++r) { bav[r] = ba[m0 + hi * 4 + r]; bbv[r] = bb[m0 + hi * 4 + r]; }
        #pragma unroll
        for (int t = 0; t < TBK; ++t)
            #pragma unroll
            for (int nt = 0; nt < 2; ++nt)
                #pragma unroll
                for (int r = 0; r < 4; ++r) { acc_a[t][nt][r] = bav[r]; acc_b[t][nt][r] = bbv[r]; }
        #pragma unroll
        for (int kb = 0; kb < 2; ++kb) {
            bf16x8 awa = *reinterpret_cast<const bf16x8*>(&WaB[(size_t)(m0 + lo) * CIN + kb * 32 + hi * 8]);
            bf16x8 awb = *reinterpret_cast<const bf16x8*>(&WbB[(size_t)(m0 + lo) * CIN + kb * 32 + hi * 8]);
            #pragma unroll
            for (int t = 0; t < TBK; ++t) {
                #pragma unroll
                for (int nt = 0; nt < 2; ++nt) {
                    bf16x8 bf = *reinterpret_cast<const bf16x8*>(
                        &xbf[(((size_t)(kb * 4 + t) * 2 + nt) * 64 + lane) * 8]);
                    acc_a[t][nt] = __builtin_amdgcn_mfma_f32_16x16x32_bf16(awa, bf, acc_a[t][nt], 0, 0, 0);
                    acc_b[t][nt] = __builtin_amdgcn_mfma_f32_16x16x32_bf16(awb, bf, acc_b[t][nt], 0, 0, 0);
                }
            }
        }
    }
    __syncthreads();   // xbf reads done; A1bf overlay

    // ---- store A1/A2 bf16 frags [t][u<22][i<64] ----
    {
        const int m0 = wave * 16;
        #pragma unroll
        for (int t = 0; t < TBK; ++t) {
            #pragma unroll
            for (int nt = 0; nt < 2; ++nt) {
                const int u = nt * 16 + lo;
                if (u < VV) {
                    uint2 va = {pk2(acc_a[t][nt][0], acc_a[t][nt][1]),
                                pk2(acc_a[t][nt][2], acc_a[t][nt][3])};
                    uint2 vb = {pk2(acc_b[t][nt][0], acc_b[t][nt][1]),
                                pk2(acc_b[t][nt][2], acc_b[t][nt][3])};
                    *reinterpret_cast<uint2*>(&A1bf[((size_t)t * VV + u) * 64 + m0 + hi * 4]) = va;
                    *reinterpret_cast<uint2*>(&A2bf[((size_t)t * VV + u) * 64 + m0 + hi * 4]) = vb;
                }
            }
        }
    }
    __syncthreads();

    // ---- P2 MFMA (wave = t): S in registers ----
    f32x4 s[2][2];
    {
        const int t = wave;
        bf16x8 zfrag;
        #pragma unroll
        for (int j = 0; j < 8; ++j) zfrag[j] = 0;
        #pragma unroll
        for (int mt = 0; mt < 2; ++mt)
            #pragma unroll
            for (int nt = 0; nt < 2; ++nt)
                #pragma unroll
                for (int r = 0; r < 4; ++r) s[mt][nt][r] = 0.f;
        #pragma unroll
        for (int kb = 0; kb < 2; ++kb) {
            bf16x8 a[2], b2[2];
            #pragma unroll
            for (int mt = 0; mt < 2; ++mt) {
                const int row = mt * 16 + lo;
                a[mt] = (row < VV) ? *reinterpret_cast<const bf16x8*>(
                            &A1bf[((size_t)t * VV + row) * 64 + kb * 32 + hi * 8]) : zfrag;
            }
            #pragma unroll
            for (int nt = 0; nt < 2; ++nt) {
                const int row = nt * 16 + lo;
                b2[nt] = (row < VV) ? *reinterpret_cast<const bf16x8*>(
                            &A2bf[((size_t)t * VV + row) * 64 + kb * 32 + hi * 8]) : zfrag;
            }
            #pragma unroll
            for (int mt = 0; mt < 2; ++mt)
                #pragma unroll
                for (int nt = 0; nt < 2; ++nt)
                    s[mt][nt] = __builtin_amdgcn_mfma_f32_16x16x32_bf16(a[mt], b2[nt], s[mt][nt], 0, 0, 0);
        }
    }
    __syncthreads();   // all A1bf/A2bf reads done; z_lds + psb may now overlay frag

    // ---- softmax (in-register) + per-wave psb zero + P3 (psb) + P4 MFMA -> z_lds ----
    {
        const int t = wave;
        bf16x8 zfrag;
        #pragma unroll
        for (int j = 0; j < 8; ++j) zfrag[j] = 0;

        // zero this wave's psb rows (wave-private; intra-wave program order suffices)
        {
            uint* pz = reinterpret_cast<uint*>(psb + (size_t)t * VV * 32);
            #pragma unroll
            for (int i = 0; i < 6; ++i) {
                int idx = i * 64 + lane;
                if (idx < (VV * 32) / 2) pz[idx] = 0u;
            }
        }

        float m[2] = {-1e30f, -1e30f};
        #pragma unroll
        for (int mt = 0; mt < 2; ++mt)
            #pragma unroll
            for (int nt = 0; nt < 2; ++nt)
                #pragma unroll
                for (int r = 0; r < 4; ++r) {
                    s[mt][nt][r] *= (1.0f / 64.0f);
                    const int u = mt * 16 + hi * 4 + r;
                    if (u < VV) m[nt] = fmaxf(m[nt], s[mt][nt][r]);
                }
        #pragma unroll
        for (int nt = 0; nt < 2; ++nt) {
            m[nt] = fmaxf(m[nt], __shfl_xor(m[nt], 16));
            m[nt] = fmaxf(m[nt], __shfl_xor(m[nt], 32));
        }
        float e[2][2][4];
        float sum[2] = {0.f, 0.f};
        #pragma unroll
        for (int mt = 0; mt < 2; ++mt)
            #pragma unroll
            for (int nt = 0; nt < 2; ++nt)
                #pragma unroll
                for (int r = 0; r < 4; ++r) {
                    const int u = mt * 16 + hi * 4 + r;
                    float ev = (u < VV) ? __expf(s[mt][nt][r] - m[nt]) : 0.f;
                    e[mt][nt][r] = ev;
                    sum[nt] += ev;
                }
        #pragma unroll
        for (int nt = 0; nt < 2; ++nt) {
            sum[nt] += __shfl_xor(sum[nt], 16);
            sum[nt] += __shfl_xor(sum[nt], 32);
        }

        // P3: P = A + 1e-6 + softmax -> psb bf16 (wave-private rows)
        {
            const float* Ag = A + ((size_t)(n * TT + t0 + t) * VV) * VV;
            #pragma unroll
            for (int nt = 0; nt < 2; ++nt) {
                const int v = nt * 16 + lo;
                if (v < VV) {
                    const float inv = 1.0f / sum[nt];
                    #pragma unroll
                    for (int mt = 0; mt < 2; ++mt)
                        #pragma unroll
                        for (int r = 0; r < 4; ++r) {
                            const int u = mt * 16 + hi * 4 + r;
                            if (u < VV)
                                psb[((size_t)t * VV + u) * 32 + v] =
                                    f2bf(Ag[u * VV + v] + 1e-6f + e[mt][nt][r] * inv);
                        }
                }
            }
        }
        // P4 MFMA: z[c][tv] -> z_lds bf16 [c][96] (tv = t*22 + u)
        {
            bf16x8 bfr[2];
            #pragma unroll
            for (int nt = 0; nt < 2; ++nt) {
                const int u = nt * 16 + lo;
                bfr[nt] = (u < VV) ? *reinterpret_cast<const bf16x8*>(
                              &psb[((size_t)t * VV + u) * 32 + hi * 8]) : zfrag;
            }
            #pragma unroll
            for (int mt = 0; mt < 4; ++mt) {
                bf16x8 a = *reinterpret_cast<const bf16x8*>(
                    &xsb[((size_t)(t * 64 + mt * 16 + lo)) * 32 + hi * 8]);
                #pragma unroll
                for (int nt = 0; nt < 2; ++nt) {
                    f32x4 acc = {0.f, 0.f, 0.f, 0.f};
                    acc = __builtin_amdgcn_mfma_f32_16x16x32_bf16(a, bfr[nt], acc, 0, 0, 0);
                    const int u = nt * 16 + lo;
                    if (u < VV) {
                        #pragma unroll
                        for (int r = 0; r < 4; ++r) {
                            const int c = mt * 16 + hi * 4 + r;
                            z_lds[(size_t)c * 96 + t * VV + u] = f2bf(acc[r]);
                        }
                    }
                }
            }
        }
    }
    __syncthreads();   // z_lds complete; xsb reads done -> zbf may overlay

    // ---- conv: z_lds -> zbf B-frags ----
    for (int it = tid; it < 768; it += 256) {
        const int kb  = it / 384;
        const int rem = it - kb * 384;
        const int nt  = rem >> 6;
        const int ln  = rem & 63;
        const int tv  = nt * 16 + (ln & 15);
        const int c0  = kb * 32 + (ln >> 4) * 8;
        ushort tmp[8];
        if (tv < ZROW) {
            #pragma unroll
            for (int j = 0; j < 8; ++j) tmp[j] = z_lds[(size_t)(c0 + j) * 96 + tv];
        } else {
            #pragma unroll
            for (int j = 0; j < 8; ++j) tmp[j] = 0;
        }
        *reinterpret_cast<uint4*>(&zbf[(size_t)it * 8]) = *reinterpret_cast<const uint4*>(tmp);
    }
    __syncthreads();

    // ---- Phase B: out = relu(Wd @ z + bd) ----
    {
        const int o0 = wave * 64;
        f32x4 acc[4][6];
        #pragma unroll
        for (int mt = 0; mt < 4; ++mt) {
            #pragma unroll
            for (int r = 0; r < 4; ++r) {
                const float b = bd[o0 + mt * 16 + hi * 4 + r];
                #pragma unroll
                for (int nt = 0; nt < 6; ++nt) acc[mt][nt][r] = b;
            }
        }
        #pragma unroll
        for (int kb = 0; kb < 2; ++kb) {
            bf16x8 bfr[6];
            #pragma unroll
            for (int nt = 0; nt < 6; ++nt)
                bfr[nt] = *reinterpret_cast<const bf16x8*>(&zbf[((kb * 6 + nt) * 64 + lane) * 8]);
            #pragma unroll
            for (int mt = 0; mt < 4; ++mt) {
                bf16x8 aw = *reinterpret_cast<const bf16x8*>(
                    &WdB[(size_t)(o0 + mt * 16 + lo) * CIN + kb * 32 + hi * 8]);
                #pragma unroll
                for (int nt = 0; nt < 6; ++nt)
                    acc[mt][nt] = __builtin_amdgcn_mfma_f32_16x16x32_bf16(aw, bfr[nt], acc[mt][nt], 0, 0, 0);
            }
        }
        #pragma unroll
        for (int mt = 0; mt < 4; ++mt) {
            #pragma unroll
            for (int nt = 0; nt < 6; ++nt) {
                const int col = nt * 16 + lo;
                if (col < ZROW) {
                    #pragma unroll
                    for (int r = 0; r < 4; ++r) {
                        const int o = o0 + mt * 16 + hi * 4 + r;
                        out[((size_t)(n * COUT + o)) * (TT * VV) + (size_t)tq * ZROW + col]
                            = fmaxf(acc[mt][nt][r], 0.f);
                    }
                }
            }
        }
    }
}

// ===================== Fallback: verified R1 monolithic kernel =====================
__global__ __launch_bounds__(256, 4) void agcn_fused(
    const float* __restrict__ x, const float* __restrict__ A,
    const float* __restrict__ Wa, const float* __restrict__ ba,
    const float* __restrict__ Wb, const float* __restrict__ bb,
    const float* __restrict__ Wd, const float* __restrict__ bd,
    float* __restrict__ out)
{
    const int t   = blockIdx.x;
    const int n   = blockIdx.y;
    const int tid = threadIdx.x;
    __shared__ float smem[7424];
    float* xs   = smem;
    float* A1s  = smem + 1536;
    float* A2s  = smem + 3072;
    float* Ssf  = smem + 4608;
    float* Psf  = smem + 5136;
    float* outs = smem;
    float* zs   = smem + 5888;

    for (int f = tid; f < CIN * VV; f += 256) {
        int c = f / VV, v = f - c * VV;
        xs[c * PAD + v] = x[(((size_t)n * CIN + c) * TT + t) * VV + v];
    }
    {
        const float* Ag = A + (((size_t)n * TT + t) * VV) * VV;
        for (int f = tid; f < VV * VV; f += 256) {
            int u = f / VV, v = f - u * VV;
            Psf[u * PAD + v] = Ag[f] + 1e-6f;
        }
    }
    __syncthreads();
    {
        const int r  = tid & 63;
        const int q  = tid >> 6;
        const int us = (q * VV) >> 2;
        const int ue = ((q + 1) * VV) >> 2;
        const float* War = Wa + r * CIN;
        const float* Wbr = Wb + r * CIN;
        float acc1[6], acc2[6];
        const float b1 = ba[r], b2 = bb[r];
        #pragma unroll
        for (int u = 0; u < 6; ++u) { acc1[u] = b1; acc2[u] = b2; }
        for (int c = 0; c < CIN; c += 4) {
            float4 wa4 = *reinterpret_cast<const float4*>(War + c);
            float4 wb4 = *reinterpret_cast<const float4*>(Wbr + c);
            #pragma unroll
            for (int u = 0; u < 6; ++u) {
                float x0 = xs[(c + 0) * PAD + us + u];
                float x1 = xs[(c + 1) * PAD + us + u];
                float x2 = xs[(c + 2) * PAD + us + u];
                float x3 = xs[(c + 3) * PAD + us + u];
                acc1[u] += wa4.x * x0 + wa4.y * x1 + wa4.z * x2 + wa4.w * x3;
                acc2[u] += wb4.x * x0 + wb4.y * x1 + wb4.z * x2 + wb4.w * x3;
            }
        }
        #pragma unroll
        for (int u = 0; u < 6; ++u) {
            if (us + u < ue) {
                A1s[r * PAD + us + u] = acc1[u];
                A2s[r * PAD + us + u] = acc2[u];
            }
        }
    }
    __syncthreads();
    for (int f = tid; f < VV * VV; f += 256) {
        int u = f / VV, v = f - u * VV;
        float s = 0.f;
        for (int i = 0; i < CIN; ++i)
            s += A1s[i * PAD + u] * A2s[i * PAD + v];
        Ssf[u * PAD + v] = s * (1.0f / 64.0f);
    }
    __syncthreads();
    if (tid < VV) {
        const int v = tid;
        float m = -1e30f;
        #pragma unroll
        for (int u = 0; u < VV; ++u) m = fmaxf(m, Ssf[u * PAD + v]);
        float sum = 0.f;
        #pragma unroll
        for (int u = 0; u < VV; ++u) sum += __expf(Ssf[u * PAD + v] - m);
        const float inv = 1.0f / sum;
        #pragma unroll
        for (int u = 0; u < VV; ++u)
            Psf[u * PAD + v] += __expf(Ssf[u * PAD + v] - m) * inv;
    }
    __syncthreads();
    for (int f = tid; f < CIN * VV; f += 256) {
        int c = f / VV, u = f - c * VV;
        float s = 0.f;
        #pragma unroll
        for (int w = 0; w < VV; ++w)
            s += Psf[u * PAD + w] * xs[c * PAD + w];
        zs[c * PAD + u] = s;
    }
    __syncthreads();
    {
        const int o = tid;
        const float* Wr = Wd + o * CIN;
        float acc[VV];
        const float b = bd[o];
        #pragma unroll
        for (int u = 0; u < VV; ++u) acc[u] = b;
        for (int c = 0; c < CIN; c += 4) {
            float4 w4 = *reinterpret_cast<const float4*>(Wr + c);
            #pragma unroll
            for (int cc = 0; cc < 4; ++cc) {
                const float w = (cc == 0) ? w4.x : (cc == 1) ? w4.y : (cc == 2) ? w4.z : w4.w;
                const float* zr = zs + (c + cc) * PAD;
                #pragma unroll
                for (int uq = 0; uq < 5; ++uq) {
                    float4 zq = *reinterpret_cast<const float4*>(zr + uq * 4);
                    acc[uq * 4 + 0] += w * zq.x;
                    acc[uq * 4 + 1] += w * zq.y;
                    acc[uq * 4 + 2] += w * zq.z;
                    acc[uq * 4 + 3] += w * zq.w;
                }
                float2 zt = *reinterpret_cast<const float2*>(zr + 20);
                acc[20] += w * zt.x;
                acc[21] += w * zt.y;
            }
        }
        #pragma unroll
        for (int u = 0; u < VV; ++u)
            outs[o * OPAD + u] = fmaxf(acc[u], 0.f);
    }
    __syncthreads();
    {
        const size_t obase = (size_t)n * COUT * TT * VV + (size_t)t * VV;
        for (int f = tid; f < COUT * VV; f += 256) {
            int o = f / VV, u = f - o * VV;
            out[obase + (size_t)o * (TT * VV) + u] = outs[o * OPAD + u];
        }
    }
}

extern "C" void kernel_launch(void* const* d_in, const int* in_sizes, int n_in,
                              void* d_out, int out_size, void* d_ws, size_t ws_size,
                              hipStream_t stream) {
    const float* x  = (const float*)d_in[0];
    const float* A  = (const float*)d_in[1];
    const float* Wa = (const float*)d_in[2];
    const float* ba = (const float*)d_in[3];
    const float* Wb = (const float*)d_in[4];
    const float* bb = (const float*)d_in[5];
    const float* Wd = (const float*)d_in[6];
    const float* bd = (const float*)d_in[7];
    float* outp     = (float*)d_out;

    const size_t wab_bytes = (size_t)CIN * CIN * sizeof(ushort);    // 8 KB each
    const size_t wdb_bytes = (size_t)COUT * CIN * sizeof(ushort);   // 32 KB

    if (ws_size >= 2 * wab_bytes + wdb_bytes) {
        ushort* wab = (ushort*)d_ws;
        ushort* wbb = (ushort*)((char*)d_ws + wab_bytes);
        ushort* wdb = (ushort*)((char*)d_ws + 2 * wab_bytes);
        const int prep_items = 2 * CIN * CIN + COUT * CIN;   // 24576
        w_to_bf16<<<(prep_items + 255) / 256, 256, 0, stream>>>(Wa, Wb, Wd, wab, wbb, wdb);
        dim3 g(NTB, NB);
        agcn_fused_mfma<<<g, 256, 0, stream>>>(x, A, wab, ba, wbb, bb, wdb, bd, outp);
    } else {
        dim3 grid(TT, NB);
        agcn_fused<<<grid, 256, 0, stream>>>(x, A, Wa, ba, Wb, bb, Wd, bd, outp);
    }
}

// Round 18
// 75.031 us; speedup vs baseline: 1.3150x; 1.3150x over previous
//
#include <hip/hip_runtime.h>

#define NB    16
#define CIN   64
#define TT    512
#define VV    22
#define COUT  256
#define TBK   4            // t per block/tile
#define NTB   (TT / TBK)   // 128
#define ZROW  (TBK * VV)   // 88
#define PAD   24           // fallback kernel pads
#define OPAD  23

typedef __attribute__((ext_vector_type(8))) short bf16x8;
typedef __attribute__((ext_vector_type(4))) float f32x4;

__device__ __forceinline__ ushort f2bf(float f) {   // RNE fp32 -> bf16
    unsigned u = __float_as_uint(f);
    return (ushort)((u + 0x7FFFu + ((u >> 16) & 1u)) >> 16);
}
__device__ __forceinline__ uint pk2(float a, float b) {
    return (uint)f2bf(a) | ((uint)f2bf(b) << 16);
}

// ===================== Prep: Wa/Wb/Wd -> bf16 (once, into ws) =====================
__global__ void w_to_bf16(const float* __restrict__ Wa, const float* __restrict__ Wb,
                          const float* __restrict__ Wd,
                          ushort* __restrict__ WaB, ushort* __restrict__ WbB,
                          ushort* __restrict__ WdB)
{
    int i = blockIdx.x * 256 + threadIdx.x;
    if (i < CIN * CIN)                 WaB[i] = f2bf(Wa[i]);
    else if (i < 2 * CIN * CIN)        WbB[i - CIN * CIN] = f2bf(Wb[i - CIN * CIN]);
    else if (i < 2 * CIN * CIN + COUT * CIN)
                                       WdB[i - 2 * CIN * CIN] = f2bf(Wd[i - 2 * CIN * CIN]);
}

// ===================== Fused kernel: LDS 38912B (4 blocks/CU via LDS), bounds (256,3) =====
// R17 lesson: (256,4) forced VGPR 84->64 and spilled Phase B's acc (FETCH +18MB, WRITE +39MB).
// (256,3) keeps the allocator budget (no spill); occupancy still reaches 4 blocks/CU because
// LDS (38912B) is the binding limit and 84 VGPR <= 128 permits 4 waves/SIMD.
// Fragment conventions (HW-validated R12/R13):
//   A-op: lane l holds A[row = tile*16 + (l&15)][k = kb*32 + (l>>4)*8 + j]
//   B-op: lane l holds B[k][col = tile*16 + (l&15)],  C/D: col = l&15, row = (l>>4)*4 + reg
__global__ __launch_bounds__(256, 3) void agcn_fused_mfma(
    const float* __restrict__ x, const float* __restrict__ A,
    const ushort* __restrict__ WaB, const float* __restrict__ ba,
    const ushort* __restrict__ WbB, const float* __restrict__ bb,
    const ushort* __restrict__ WdB, const float* __restrict__ bd,
    float* __restrict__ out)
{
    const int bx = blockIdx.x;                   // 0..127
    const int tq = (bx & 7) * 16 + (bx >> 3);    // XCD swizzle
    const int n  = blockIdx.y;
    const int tid = threadIdx.x;
    const int lane = tid & 63, wave = tid >> 6;
    const int hi = lane >> 4, lo = lane & 15;
    const int t0 = tq * TBK;

    // LDS 38912B total: xsb 16384 | frag 22528.
    // frag timeline: xbf(16384) -> A1bf+A2bf(22528) -> z_lds(12288) + psb(5632 @ +12288)
    __shared__ __align__(16) ushort xsb[TBK * 64 * 32];   // [t][c][w<32]; zbf overlays in phase B
    __shared__ __align__(16) ushort frag[11264];
    ushort* xbf   = frag;            // P1 B-frags [kb2][t4][nt2][ln64][8] = 8192 us
    ushort* A1bf  = frag;            // [t][u<22][i<64] = 5632 us
    ushort* A2bf  = frag + 5632;
    ushort* z_lds = frag;            // bf16 [c<64][96] = 6144 us (post-P2)
    ushort* psb   = frag + 6144;     // [t][u<22][w<32] = 2816 us (post-P2, wave-private per t)
    ushort* zbf   = xsb;             // [kb2][nt6][ln64][8] = 6144 us (phase B)

    // ---- zero xsb pads (cols 22..31) ----
    for (int i = tid; i < TBK * 64 * 5; i += 256) {
        int row = i / 5, q = i - row * 5;
        reinterpret_cast<uint*>(&xsb[row * 32 + 22])[q] = 0u;
    }

    // ---- P0: stage x (352B-contiguous per c) -> bf16 LDS ----
    {
        const float* xsrc = x + ((size_t)n * CIN * TT + t0) * VV;
        for (int i4 = tid; i4 < CIN * 22; i4 += 256) {
            int c = i4 / 22, q = i4 - c * 22;
            float4 v4 = *reinterpret_cast<const float4*>(xsrc + (size_t)c * (TT * VV) + q * 4);
            #pragma unroll
            for (int j = 0; j < 4; ++j) {
                int e  = q * 4 + j;
                int tt = e / 22, v = e - tt * 22;
                float val = (j == 0) ? v4.x : (j == 1) ? v4.y : (j == 2) ? v4.z : v4.w;
                xsb[(tt * 64 + c) * 32 + v] = f2bf(val);
            }
        }
    }
    __syncthreads();

    // ---- conv1: P1 B-frags from xsb ----
    for (int it = tid; it < 1024; it += 256) {
        int kb = it >> 9;
        int t  = (it >> 7) & 3;
        int nt = (it >> 6) & 1;
        int ln = it & 63;
        int v  = nt * 16 + (ln & 15);
        int c0 = kb * 32 + (ln >> 4) * 8;
        ushort tmp[8];
        #pragma unroll
        for (int j = 0; j < 8; ++j) tmp[j] = xsb[(t * 64 + c0 + j) * 32 + v];
        *reinterpret_cast<uint4*>(&xbf[(size_t)it * 8]) = *reinterpret_cast<const uint4*>(tmp);
    }
    __syncthreads();

    // ---- P1 MFMA: A1 = Wa@X+ba, A2 = Wb@X+bb for all 4 t's ----
    f32x4 acc_a[TBK][2], acc_b[TBK][2];
    {
        const int m0 = wave * 16;
        float bav[4], bbv[4];
        #pragma unroll
        for (int r = 0; r < 4; ++r) { bav[r] = ba[m0 + hi * 4 + r]; bbv[r] = bb[m0 + hi * 4 + r]; }
        #pragma unroll
        for (int t = 0; t < TBK; ++t)
            #pragma unroll
            for (int nt = 0; nt < 2; ++nt)
                #pragma unroll
                for (int r = 0; r < 4; ++r) { acc_a[t][nt][r] = bav[r]; acc_b[t][nt][r] = bbv[r]; }
        #pragma unroll
        for (int kb = 0; kb < 2; ++kb) {
            bf16x8 awa = *reinterpret_cast<const bf16x8*>(&WaB[(size_t)(m0 + lo) * CIN + kb * 32 + hi * 8]);
            bf16x8 awb = *reinterpret_cast<const bf16x8*>(&WbB[(size_t)(m0 + lo) * CIN + kb * 32 + hi * 8]);
            #pragma unroll
            for (int t = 0; t < TBK; ++t) {
                #pragma unroll
                for (int nt = 0; nt < 2; ++nt) {
                    bf16x8 bf = *reinterpret_cast<const bf16x8*>(
                        &xbf[(((size_t)(kb * 4 + t) * 2 + nt) * 64 + lane) * 8]);
                    acc_a[t][nt] = __builtin_amdgcn_mfma_f32_16x16x32_bf16(awa, bf, acc_a[t][nt], 0, 0, 0);
                    acc_b[t][nt] = __builtin_amdgcn_mfma_f32_16x16x32_bf16(awb, bf, acc_b[t][nt], 0, 0, 0);
                }
            }
        }
    }
    __syncthreads();   // xbf reads done; A1bf overlay

    // ---- store A1/A2 bf16 frags [t][u<22][i<64] ----
    {
        const int m0 = wave * 16;
        #pragma unroll
        for (int t = 0; t < TBK; ++t) {
            #pragma unroll
            for (int nt = 0; nt < 2; ++nt) {
                const int u = nt * 16 + lo;
                if (u < VV) {
                    uint2 va = {pk2(acc_a[t][nt][0], acc_a[t][nt][1]),
                                pk2(acc_a[t][nt][2], acc_a[t][nt][3])};
                    uint2 vb = {pk2(acc_b[t][nt][0], acc_b[t][nt][1]),
                                pk2(acc_b[t][nt][2], acc_b[t][nt][3])};
                    *reinterpret_cast<uint2*>(&A1bf[((size_t)t * VV + u) * 64 + m0 + hi * 4]) = va;
                    *reinterpret_cast<uint2*>(&A2bf[((size_t)t * VV + u) * 64 + m0 + hi * 4]) = vb;
                }
            }
        }
    }
    __syncthreads();

    // ---- P2 MFMA (wave = t): S in registers ----
    f32x4 s[2][2];
    {
        const int t = wave;
        bf16x8 zfrag;
        #pragma unroll
        for (int j = 0; j < 8; ++j) zfrag[j] = 0;
        #pragma unroll
        for (int mt = 0; mt < 2; ++mt)
            #pragma unroll
            for (int nt = 0; nt < 2; ++nt)
                #pragma unroll
                for (int r = 0; r < 4; ++r) s[mt][nt][r] = 0.f;
        #pragma unroll
        for (int kb = 0; kb < 2; ++kb) {
            bf16x8 a[2], b2[2];
            #pragma unroll
            for (int mt = 0; mt < 2; ++mt) {
                const int row = mt * 16 + lo;
                a[mt] = (row < VV) ? *reinterpret_cast<const bf16x8*>(
                            &A1bf[((size_t)t * VV + row) * 64 + kb * 32 + hi * 8]) : zfrag;
            }
            #pragma unroll
            for (int nt = 0; nt < 2; ++nt) {
                const int row = nt * 16 + lo;
                b2[nt] = (row < VV) ? *reinterpret_cast<const bf16x8*>(
                            &A2bf[((size_t)t * VV + row) * 64 + kb * 32 + hi * 8]) : zfrag;
            }
            #pragma unroll
            for (int mt = 0; mt < 2; ++mt)
                #pragma unroll
                for (int nt = 0; nt < 2; ++nt)
                    s[mt][nt] = __builtin_amdgcn_mfma_f32_16x16x32_bf16(a[mt], b2[nt], s[mt][nt], 0, 0, 0);
        }
    }
    __syncthreads();   // all A1bf/A2bf reads done; z_lds + psb may now overlay frag

    // ---- softmax (in-register) + per-wave psb zero + P3 (psb) + P4 MFMA -> z_lds ----
    {
        const int t = wave;
        bf16x8 zfrag;
        #pragma unroll
        for (int j = 0; j < 8; ++j) zfrag[j] = 0;

        // zero this wave's psb rows (wave-private; intra-wave program order suffices)
        {
            uint* pz = reinterpret_cast<uint*>(psb + (size_t)t * VV * 32);
            #pragma unroll
            for (int i = 0; i < 6; ++i) {
                int idx = i * 64 + lane;
                if (idx < (VV * 32) / 2) pz[idx] = 0u;
            }
        }

        float m[2] = {-1e30f, -1e30f};
        #pragma unroll
        for (int mt = 0; mt < 2; ++mt)
            #pragma unroll
            for (int nt = 0; nt < 2; ++nt)
                #pragma unroll
                for (int r = 0; r < 4; ++r) {
                    s[mt][nt][r] *= (1.0f / 64.0f);
                    const int u = mt * 16 + hi * 4 + r;
                    if (u < VV) m[nt] = fmaxf(m[nt], s[mt][nt][r]);
                }
        #pragma unroll
        for (int nt = 0; nt < 2; ++nt) {
            m[nt] = fmaxf(m[nt], __shfl_xor(m[nt], 16));
            m[nt] = fmaxf(m[nt], __shfl_xor(m[nt], 32));
        }
        float e[2][2][4];
        float sum[2] = {0.f, 0.f};
        #pragma unroll
        for (int mt = 0; mt < 2; ++mt)
            #pragma unroll
            for (int nt = 0; nt < 2; ++nt)
                #pragma unroll
                for (int r = 0; r < 4; ++r) {
                    const int u = mt * 16 + hi * 4 + r;
                    float ev = (u < VV) ? __expf(s[mt][nt][r] - m[nt]) : 0.f;
                    e[mt][nt][r] = ev;
                    sum[nt] += ev;
                }
        #pragma unroll
        for (int nt = 0; nt < 2; ++nt) {
            sum[nt] += __shfl_xor(sum[nt], 16);
            sum[nt] += __shfl_xor(sum[nt], 32);
        }

        // P3: P = A + 1e-6 + softmax -> psb bf16 (wave-private rows)
        {
            const float* Ag = A + ((size_t)(n * TT + t0 + t) * VV) * VV;
            #pragma unroll
            for (int nt = 0; nt < 2; ++nt) {
                const int v = nt * 16 + lo;
                if (v < VV) {
                    const float inv = 1.0f / sum[nt];
                    #pragma unroll
                    for (int mt = 0; mt < 2; ++mt)
                        #pragma unroll
                        for (int r = 0; r < 4; ++r) {
                            const int u = mt * 16 + hi * 4 + r;
                            if (u < VV)
                                psb[((size_t)t * VV + u) * 32 + v] =
                                    f2bf(Ag[u * VV + v] + 1e-6f + e[mt][nt][r] * inv);
                        }
                }
            }
        }
        // P4 MFMA: z[c][tv] -> z_lds bf16 [c][96] (tv = t*22 + u)
        {
            bf16x8 bfr[2];
            #pragma unroll
            for (int nt = 0; nt < 2; ++nt) {
                const int u = nt * 16 + lo;
                bfr[nt] = (u < VV) ? *reinterpret_cast<const bf16x8*>(
                              &psb[((size_t)t * VV + u) * 32 + hi * 8]) : zfrag;
            }
            #pragma unroll
            for (int mt = 0; mt < 4; ++mt) {
                bf16x8 a = *reinterpret_cast<const bf16x8*>(
                    &xsb[((size_t)(t * 64 + mt * 16 + lo)) * 32 + hi * 8]);
                #pragma unroll
                for (int nt = 0; nt < 2; ++nt) {
                    f32x4 acc = {0.f, 0.f, 0.f, 0.f};
                    acc = __builtin_amdgcn_mfma_f32_16x16x32_bf16(a, bfr[nt], acc, 0, 0, 0);
                    const int u = nt * 16 + lo;
                    if (u < VV) {
                        #pragma unroll
                        for (int r = 0; r < 4; ++r) {
                            const int c = mt * 16 + hi * 4 + r;
                            z_lds[(size_t)c * 96 + t * VV + u] = f2bf(acc[r]);
                        }
                    }
                }
            }
        }
    }
    __syncthreads();   // z_lds complete; xsb reads done -> zbf may overlay

    // ---- conv: z_lds -> zbf B-frags ----
    for (int it = tid; it < 768; it += 256) {
        const int kb  = it / 384;
        const int rem = it - kb * 384;
        const int nt  = rem >> 6;
        const int ln  = rem & 63;
        const int tv  = nt * 16 + (ln & 15);
        const int c0  = kb * 32 + (ln >> 4) * 8;
        ushort tmp[8];
        if (tv < ZROW) {
            #pragma unroll
            for (int j = 0; j < 8; ++j) tmp[j] = z_lds[(size_t)(c0 + j) * 96 + tv];
        } else {
            #pragma unroll
            for (int j = 0; j < 8; ++j) tmp[j] = 0;
        }
        *reinterpret_cast<uint4*>(&zbf[(size_t)it * 8]) = *reinterpret_cast<const uint4*>(tmp);
    }
    __syncthreads();

    // ---- Phase B: out = relu(Wd @ z + bd) ----
    {
        const int o0 = wave * 64;
        f32x4 acc[4][6];
        #pragma unroll
        for (int mt = 0; mt < 4; ++mt) {
            #pragma unroll
            for (int r = 0; r < 4; ++r) {
                const float b = bd[o0 + mt * 16 + hi * 4 + r];
                #pragma unroll
                for (int nt = 0; nt < 6; ++nt) acc[mt][nt][r] = b;
            }
        }
        #pragma unroll
        for (int kb = 0; kb < 2; ++kb) {
            bf16x8 bfr[6];
            #pragma unroll
            for (int nt = 0; nt < 6; ++nt)
                bfr[nt] = *reinterpret_cast<const bf16x8*>(&zbf[((kb * 6 + nt) * 64 + lane) * 8]);
            #pragma unroll
            for (int mt = 0; mt < 4; ++mt) {
                bf16x8 aw = *reinterpret_cast<const bf16x8*>(
                    &WdB[(size_t)(o0 + mt * 16 + lo) * CIN + kb * 32 + hi * 8]);
                #pragma unroll
                for (int nt = 0; nt < 6; ++nt)
                    acc[mt][nt] = __builtin_amdgcn_mfma_f32_16x16x32_bf16(aw, bfr[nt], acc[mt][nt], 0, 0, 0);
            }
        }
        #pragma unroll
        for (int mt = 0; mt < 4; ++mt) {
            #pragma unroll
            for (int nt = 0; nt < 6; ++nt) {
                const int col = nt * 16 + lo;
                if (col < ZROW) {
                    #pragma unroll
                    for (int r = 0; r < 4; ++r) {
                        const int o = o0 + mt * 16 + hi * 4 + r;
                        out[((size_t)(n * COUT + o)) * (TT * VV) + (size_t)tq * ZROW + col]
                            = fmaxf(acc[mt][nt][r], 0.f);
                    }
                }
            }
        }
    }
}

// ===================== Fallback: verified R1 monolithic kernel =====================
__global__ __launch_bounds__(256, 4) void agcn_fused(
    const float* __restrict__ x, const float* __restrict__ A,
    const float* __restrict__ Wa, const float* __restrict__ ba,
    const float* __restrict__ Wb, const float* __restrict__ bb,
    const float* __restrict__ Wd, const float* __restrict__ bd,
    float* __restrict__ out)
{
    const int t   = blockIdx.x;
    const int n   = blockIdx.y;
    const int tid = threadIdx.x;
    __shared__ float smem[7424];
    float* xs   = smem;
    float* A1s  = smem + 1536;
    float* A2s  = smem + 3072;
    float* Ssf  = smem + 4608;
    float* Psf  = smem + 5136;
    float* outs = smem;
    float* zs   = smem + 5888;

    for (int f = tid; f < CIN * VV; f += 256) {
        int c = f / VV, v = f - c * VV;
        xs[c * PAD + v] = x[(((size_t)n * CIN + c) * TT + t) * VV + v];
    }
    {
        const float* Ag = A + (((size_t)n * TT + t) * VV) * VV;
        for (int f = tid; f < VV * VV; f += 256) {
            int u = f / VV, v = f - u * VV;
            Psf[u * PAD + v] = Ag[f] + 1e-6f;
        }
    }
    __syncthreads();
    {
        const int r  = tid & 63;
        const int q  = tid >> 6;
        const int us = (q * VV) >> 2;
        const int ue = ((q + 1) * VV) >> 2;
        const float* War = Wa + r * CIN;
        const float* Wbr = Wb + r * CIN;
        float acc1[6], acc2[6];
        const float b1 = ba[r], b2 = bb[r];
        #pragma unroll
        for (int u = 0; u < 6; ++u) { acc1[u] = b1; acc2[u] = b2; }
        for (int c = 0; c < CIN; c += 4) {
            float4 wa4 = *reinterpret_cast<const float4*>(War + c);
            float4 wb4 = *reinterpret_cast<const float4*>(Wbr + c);
            #pragma unroll
            for (int u = 0; u < 6; ++u) {
                float x0 = xs[(c + 0) * PAD + us + u];
                float x1 = xs[(c + 1) * PAD + us + u];
                float x2 = xs[(c + 2) * PAD + us + u];
                float x3 = xs[(c + 3) * PAD + us + u];
                acc1[u] += wa4.x * x0 + wa4.y * x1 + wa4.z * x2 + wa4.w * x3;
                acc2[u] += wb4.x * x0 + wb4.y * x1 + wb4.z * x2 + wb4.w * x3;
            }
        }
        #pragma unroll
        for (int u = 0; u < 6; ++u) {
            if (us + u < ue) {
                A1s[r * PAD + us + u] = acc1[u];
                A2s[r * PAD + us + u] = acc2[u];
            }
        }
    }
    __syncthreads();
    for (int f = tid; f < VV * VV; f += 256) {
        int u = f / VV, v = f - u * VV;
        float s = 0.f;
        for (int i = 0; i < CIN; ++i)
            s += A1s[i * PAD + u] * A2s[i * PAD + v];
        Ssf[u * PAD + v] = s * (1.0f / 64.0f);
    }
    __syncthreads();
    if (tid < VV) {
        const int v = tid;
        float m = -1e30f;
        #pragma unroll
        for (int u = 0; u < VV; ++u) m = fmaxf(m, Ssf[u * PAD + v]);
        float sum = 0.f;
        #pragma unroll
        for (int u = 0; u < VV; ++u) sum += __expf(Ssf[u * PAD + v] - m);
        const float inv = 1.0f / sum;
        #pragma unroll
        for (int u = 0; u < VV; ++u)
            Psf[u * PAD + v] += __expf(Ssf[u * PAD + v] - m) * inv;
    }
    __syncthreads();
    for (int f = tid; f < CIN * VV; f += 256) {
        int c = f / VV, u = f - c * VV;
        float s = 0.f;
        #pragma unroll
        for (int w = 0; w < VV; ++w)
            s += Psf[u * PAD + w] * xs[c * PAD + w];
        zs[c * PAD + u] = s;
    }
    __syncthreads();
    {
        const int o = tid;
        const float* Wr = Wd + o * CIN;
        float acc[VV];
        const float b = bd[o];
        #pragma unroll
        for (int u = 0; u < VV; ++u) acc[u] = b;
        for (int c = 0; c < CIN; c += 4) {
            float4 w4 = *reinterpret_cast<const float4*>(Wr + c);
            #pragma unroll
            for (int cc = 0; cc < 4; ++cc) {
                const float w = (cc == 0) ? w4.x : (cc == 1) ? w4.y : (cc == 2) ? w4.z : w4.w;
                const float* zr = zs + (c + cc) * PAD;
                #pragma unroll
                for (int uq = 0; uq < 5; ++uq) {
                    float4 zq = *reinterpret_cast<const float4*>(zr + uq * 4);
                    acc[uq * 4 + 0] += w * zq.x;
                    acc[uq * 4 + 1] += w * zq.y;
                    acc[uq * 4 + 2] += w * zq.z;
                    acc[uq * 4 + 3] += w * zq.w;
                }
                float2 zt = *reinterpret_cast<const float2*>(zr + 20);
                acc[20] += w * zt.x;
                acc[21] += w * zt.y;
            }
        }
        #pragma unroll
        for (int u = 0; u < VV; ++u)
            outs[o * OPAD + u] = fmaxf(acc[u], 0.f);
    }
    __syncthreads();
    {
        const size_t obase = (size_t)n * COUT * TT * VV + (size_t)t * VV;
        for (int f = tid; f < COUT * VV; f += 256) {
            int o = f / VV, u = f - o * VV;
            out[obase + (size_t)o * (TT * VV) + u] = outs[o * OPAD + u];
        }
    }
}

extern "C" void kernel_launch(void* const* d_in, const int* in_sizes, int n_in,
                              void* d_out, int out_size, void* d_ws, size_t ws_size,
                              hipStream_t stream) {
    const float* x  = (const float*)d_in[0];
    const float* A  = (const float*)d_in[1];
    const float* Wa = (const float*)d_in[2];
    const float* ba = (const float*)d_in[3];
    const float* Wb = (const float*)d_in[4];
    const float* bb = (const float*)d_in[5];
    const float* Wd = (const float*)d_in[6];
    const float* bd = (const float*)d_in[7];
    float* outp     = (float*)d_out;

    const size_t wab_bytes = (size_t)CIN * CIN * sizeof(ushort);    // 8 KB each
    const size_t wdb_bytes = (size_t)COUT * CIN * sizeof(ushort);   // 32 KB

    if (ws_size >= 2 * wab_bytes + wdb_bytes) {
        ushort* wab = (ushort*)d_ws;
        ushort* wbb = (ushort*)((char*)d_ws + wab_bytes);
        ushort* wdb = (ushort*)((char*)d_ws + 2 * wab_bytes);
        const int prep_items = 2 * CIN * CIN + COUT * CIN;   // 24576
        w_to_bf16<<<(prep_items + 255) / 256, 256, 0, stream>>>(Wa, Wb, Wd, wab, wbb, wdb);
        dim3 g(NTB, NB);
        agcn_fused_mfma<<<g, 256, 0, stream>>>(x, A, wab, ba, wbb, bb, wdb, bd, outp);
    } else {
        dim3 grid(TT, NB);
        agcn_fused<<<grid, 256, 0, stream>>>(x, A, Wa, ba, Wb, bb, Wd, bd, outp);
    }
}

// Round 19
// 62.838 us; speedup vs baseline: 1.5702x; 1.1940x over previous
//
#include <hip/hip_runtime.h>

#define NB    16
#define CIN   64
#define TT    512
#define VV    22
#define COUT  256
#define TBK   8            // t per block/tile
#define NTB   (TT / TBK)   // 64
#define ZROW  (TBK * VV)   // 176 = 11*16 (no tail!)
#define PAD   24           // fallback kernel pads
#define OPAD  23

typedef __attribute__((ext_vector_type(8))) short bf16x8;
typedef __attribute__((ext_vector_type(4))) float f32x4;

__device__ __forceinline__ ushort f2bf(float f) {   // RNE fp32 -> bf16
    unsigned u = __float_as_uint(f);
    return (ushort)((u + 0x7FFFu + ((u >> 16) & 1u)) >> 16);
}
__device__ __forceinline__ uint pk2(float a, float b) {
    return (uint)f2bf(a) | ((uint)f2bf(b) << 16);
}

// ===================== Prep: Wa/Wb/Wd -> bf16 (once, into ws) =====================
__global__ void w_to_bf16(const float* __restrict__ Wa, const float* __restrict__ Wb,
                          const float* __restrict__ Wd,
                          ushort* __restrict__ WaB, ushort* __restrict__ WbB,
                          ushort* __restrict__ WdB)
{
    int i = blockIdx.x * 256 + threadIdx.x;
    if (i < CIN * CIN)                 WaB[i] = f2bf(Wa[i]);
    else if (i < 2 * CIN * CIN)        WbB[i - CIN * CIN] = f2bf(Wb[i - CIN * CIN]);
    else if (i < 2 * CIN * CIN + COUT * CIN)
                                       WdB[i - 2 * CIN * CIN] = f2bf(Wd[i - 2 * CIN * CIN]);
}

// ===================== Fused kernel: TBK=8, 512 threads, 2 blocks/CU (16 waves/CU) =====
// R18 structure scaled 2x: same phases, same overlays, barriers amortized over 8 t's.
// Waves 0-3: Wa rows 16w..; waves 4-7: Wb rows. P2/P4: wave = t (8 waves, 8 t's).
// Phase B: wave owns 32 o's, streams nt=0..10 with acc[2] (no spill pressure).
// Fragment conventions (HW-validated R12/R13):
//   A-op: lane l holds A[row = tile*16 + (l&15)][k = kb*32 + (l>>4)*8 + j]
//   B-op: lane l holds B[k][col = tile*16 + (l&15)],  C/D: col = l&15, row = (l>>4)*4 + reg
__global__ __launch_bounds__(512, 2) void agcn_fused_mfma(
    const float* __restrict__ x, const float* __restrict__ A,
    const ushort* __restrict__ WaB, const float* __restrict__ ba,
    const ushort* __restrict__ WbB, const float* __restrict__ bb,
    const ushort* __restrict__ WdB, const float* __restrict__ bd,
    float* __restrict__ out)
{
    const int bx = blockIdx.x;                   // 0..63
    const int tq = (bx & 7) * 8 + (bx >> 3);     // XCD swizzle (bijective on 0..63)
    const int n  = blockIdx.y;
    const int tid = threadIdx.x;
    const int lane = tid & 63, wave = tid >> 6;  // 8 waves
    const int hi = lane >> 4, lo = lane & 15;
    const int t0 = tq * TBK;

    // LDS 77824B: xsb 32768B | frag 45056B.
    // frag timeline: xbf(32768B) -> A1bf+A2bf(45056B) -> z_lds(22528B)+psb(11264B)
    __shared__ __align__(16) ushort xsb[TBK * 64 * 32];   // [t][c][w<32]; zbf overlays in phase B
    __shared__ __align__(16) ushort frag[22528];
    ushort* xbf   = frag;            // P1 B-frags [kb2][t8][nt2][ln64][8] = 16384 us
    ushort* A1bf  = frag;            // [t8][u<22][i<64] = 11264 us
    ushort* A2bf  = frag + 11264;    // [t8][u<22][i<64] = 11264 us
    ushort* z_lds = frag;            // bf16 [c<64][176] = 11264 us (post-P2)
    ushort* psb   = frag + 11264;    // [t8][u<22][w<32] = 5632 us (post-P2, wave-private per t)
    ushort* zbf   = xsb;             // [kb2][nt11][ln64][8] = 11264 us (phase B)

    // ---- zero xsb pads (cols 22..31) ----
    for (int i = tid; i < TBK * 64 * 5; i += 512) {
        int row = i / 5, q = i - row * 5;
        reinterpret_cast<uint*>(&xsb[row * 32 + 22])[q] = 0u;
    }

    // ---- P0: stage x (704B-contiguous per c) -> bf16 LDS ----
    {
        const float* xsrc = x + ((size_t)n * CIN * TT + t0) * VV;
        for (int i4 = tid; i4 < CIN * 44; i4 += 512) {    // 44 float4 per c
            int c = i4 / 44, q = i4 - c * 44;
            float4 v4 = *reinterpret_cast<const float4*>(xsrc + (size_t)c * (TT * VV) + q * 4);
            #pragma unroll
            for (int j = 0; j < 4; ++j) {
                int e  = q * 4 + j;                       // 0..175
                int tt = e / 22, v = e - tt * 22;
                float val = (j == 0) ? v4.x : (j == 1) ? v4.y : (j == 2) ? v4.z : v4.w;
                xsb[(tt * 64 + c) * 32 + v] = f2bf(val);
            }
        }
    }
    __syncthreads();

    // ---- conv1: P1 B-frags from xsb ----
    for (int it = tid; it < 2048; it += 512) {            // [kb2][t8][nt2][ln64]
        int kb = it >> 10;
        int t  = (it >> 7) & 7;
        int nt = (it >> 6) & 1;
        int ln = it & 63;
        int v  = nt * 16 + (ln & 15);                     // <32, pads zero
        int c0 = kb * 32 + (ln >> 4) * 8;
        ushort tmp[8];
        #pragma unroll
        for (int j = 0; j < 8; ++j) tmp[j] = xsb[(t * 64 + c0 + j) * 32 + v];
        *reinterpret_cast<uint4*>(&xbf[(size_t)it * 8]) = *reinterpret_cast<const uint4*>(tmp);
    }
    __syncthreads();

    // ---- P1 MFMA: waves 0-3 -> A1 = Wa@X+ba; waves 4-7 -> A2 = Wb@X+bb (all 8 t) ----
    f32x4 acc[TBK][2];
    {
        const int isB = wave >> 2;
        const int m0  = (wave & 3) * 16;
        const ushort* W  = isB ? WbB : WaB;
        const float*  bv = isB ? bb  : ba;
        float bias[4];
        #pragma unroll
        for (int r = 0; r < 4; ++r) bias[r] = bv[m0 + hi * 4 + r];
        #pragma unroll
        for (int t = 0; t < TBK; ++t)
            #pragma unroll
            for (int nt = 0; nt < 2; ++nt)
                #pragma unroll
                for (int r = 0; r < 4; ++r) acc[t][nt][r] = bias[r];
        #pragma unroll
        for (int kb = 0; kb < 2; ++kb) {
            bf16x8 aw = *reinterpret_cast<const bf16x8*>(&W[(size_t)(m0 + lo) * CIN + kb * 32 + hi * 8]);
            #pragma unroll
            for (int t = 0; t < TBK; ++t) {
                #pragma unroll
                for (int nt = 0; nt < 2; ++nt) {
                    bf16x8 bf = *reinterpret_cast<const bf16x8*>(
                        &xbf[(((size_t)(kb * 8 + t) * 2 + nt) * 64 + lane) * 8]);
                    acc[t][nt] = __builtin_amdgcn_mfma_f32_16x16x32_bf16(aw, bf, acc[t][nt], 0, 0, 0);
                }
            }
        }
    }
    __syncthreads();   // xbf reads done; A1bf/A2bf overlay

    // ---- store A1/A2 bf16 frags [t][u<22][i<64] ----
    {
        const int isB = wave >> 2;
        const int m0  = (wave & 3) * 16;
        ushort* dst = isB ? A2bf : A1bf;
        #pragma unroll
        for (int t = 0; t < TBK; ++t) {
            #pragma unroll
            for (int nt = 0; nt < 2; ++nt) {
                const int u = nt * 16 + lo;
                if (u < VV) {
                    uint2 va = {pk2(acc[t][nt][0], acc[t][nt][1]),
                                pk2(acc[t][nt][2], acc[t][nt][3])};
                    *reinterpret_cast<uint2*>(&dst[((size_t)t * VV + u) * 64 + m0 + hi * 4]) = va;
                }
            }
        }
    }
    __syncthreads();

    // ---- P2 MFMA (wave = t): S in registers ----
    f32x4 s[2][2];
    {
        const int t = wave;
        bf16x8 zfrag;
        #pragma unroll
        for (int j = 0; j < 8; ++j) zfrag[j] = 0;
        #pragma unroll
        for (int mt = 0; mt < 2; ++mt)
            #pragma unroll
            for (int nt = 0; nt < 2; ++nt)
                #pragma unroll
                for (int r = 0; r < 4; ++r) s[mt][nt][r] = 0.f;
        #pragma unroll
        for (int kb = 0; kb < 2; ++kb) {
            bf16x8 a[2], b2[2];
            #pragma unroll
            for (int mt = 0; mt < 2; ++mt) {
                const int row = mt * 16 + lo;
                a[mt] = (row < VV) ? *reinterpret_cast<const bf16x8*>(
                            &A1bf[((size_t)t * VV + row) * 64 + kb * 32 + hi * 8]) : zfrag;
            }
            #pragma unroll
            for (int nt = 0; nt < 2; ++nt) {
                const int row = nt * 16 + lo;
                b2[nt] = (row < VV) ? *reinterpret_cast<const bf16x8*>(
                            &A2bf[((size_t)t * VV + row) * 64 + kb * 32 + hi * 8]) : zfrag;
            }
            #pragma unroll
            for (int mt = 0; mt < 2; ++mt)
                #pragma unroll
                for (int nt = 0; nt < 2; ++nt)
                    s[mt][nt] = __builtin_amdgcn_mfma_f32_16x16x32_bf16(a[mt], b2[nt], s[mt][nt], 0, 0, 0);
        }
    }
    __syncthreads();   // A-frag reads done; z_lds + psb may overlay frag

    // ---- softmax (in-register) + per-wave psb zero + P3 + P4 MFMA -> z_lds ----
    {
        const int t = wave;
        bf16x8 zfrag;
        #pragma unroll
        for (int j = 0; j < 8; ++j) zfrag[j] = 0;

        // zero this wave's psb rows (wave-private)
        {
            uint* pz = reinterpret_cast<uint*>(psb + (size_t)t * VV * 32);
            #pragma unroll
            for (int i = 0; i < 6; ++i) {
                int idx = i * 64 + lane;
                if (idx < (VV * 32) / 2) pz[idx] = 0u;
            }
        }

        float m[2] = {-1e30f, -1e30f};
        #pragma unroll
        for (int mt = 0; mt < 2; ++mt)
            #pragma unroll
            for (int nt = 0; nt < 2; ++nt)
                #pragma unroll
                for (int r = 0; r < 4; ++r) {
                    s[mt][nt][r] *= (1.0f / 64.0f);
                    const int u = mt * 16 + hi * 4 + r;
                    if (u < VV) m[nt] = fmaxf(m[nt], s[mt][nt][r]);
                }
        #pragma unroll
        for (int nt = 0; nt < 2; ++nt) {
            m[nt] = fmaxf(m[nt], __shfl_xor(m[nt], 16));
            m[nt] = fmaxf(m[nt], __shfl_xor(m[nt], 32));
        }
        float e[2][2][4];
        float sum[2] = {0.f, 0.f};
        #pragma unroll
        for (int mt = 0; mt < 2; ++mt)
            #pragma unroll
            for (int nt = 0; nt < 2; ++nt)
                #pragma unroll
                for (int r = 0; r < 4; ++r) {
                    const int u = mt * 16 + hi * 4 + r;
                    float ev = (u < VV) ? __expf(s[mt][nt][r] - m[nt]) : 0.f;
                    e[mt][nt][r] = ev;
                    sum[nt] += ev;
                }
        #pragma unroll
        for (int nt = 0; nt < 2; ++nt) {
            sum[nt] += __shfl_xor(sum[nt], 16);
            sum[nt] += __shfl_xor(sum[nt], 32);
        }

        // P3: P = A + 1e-6 + softmax -> psb bf16 (wave-private rows)
        {
            const float* Ag = A + ((size_t)(n * TT + t0 + t) * VV) * VV;
            #pragma unroll
            for (int nt = 0; nt < 2; ++nt) {
                const int v = nt * 16 + lo;
                if (v < VV) {
                    const float inv = 1.0f / sum[nt];
                    #pragma unroll
                    for (int mt = 0; mt < 2; ++mt)
                        #pragma unroll
                        for (int r = 0; r < 4; ++r) {
                            const int u = mt * 16 + hi * 4 + r;
                            if (u < VV)
                                psb[((size_t)t * VV + u) * 32 + v] =
                                    f2bf(Ag[u * VV + v] + 1e-6f + e[mt][nt][r] * inv);
                        }
                }
            }
        }
        // P4 MFMA: z[c][tv] -> z_lds bf16 [c][176] (tv = t*22 + u)
        {
            bf16x8 bfr[2];
            #pragma unroll
            for (int nt = 0; nt < 2; ++nt) {
                const int u = nt * 16 + lo;
                bfr[nt] = (u < VV) ? *reinterpret_cast<const bf16x8*>(
                              &psb[((size_t)t * VV + u) * 32 + hi * 8]) : zfrag;
            }
            #pragma unroll
            for (int mt = 0; mt < 4; ++mt) {
                bf16x8 a = *reinterpret_cast<const bf16x8*>(
                    &xsb[((size_t)(t * 64 + mt * 16 + lo)) * 32 + hi * 8]);
                #pragma unroll
                for (int nt = 0; nt < 2; ++nt) {
                    f32x4 acc4 = {0.f, 0.f, 0.f, 0.f};
                    acc4 = __builtin_amdgcn_mfma_f32_16x16x32_bf16(a, bfr[nt], acc4, 0, 0, 0);
                    const int u = nt * 16 + lo;
                    if (u < VV) {
                        #pragma unroll
                        for (int r = 0; r < 4; ++r) {
                            const int c = mt * 16 + hi * 4 + r;
                            z_lds[(size_t)c * ZROW + t * VV + u] = f2bf(acc4[r]);
                        }
                    }
                }
            }
        }
    }
    __syncthreads();   // z_lds complete; xsb reads done -> zbf may overlay

    // ---- conv: z_lds -> zbf B-frags [kb2][nt11][ln64] ----
    for (int it = tid; it < 1408; it += 512) {
        const int kb  = it / 704;
        const int rem = it - kb * 704;
        const int nt  = rem >> 6;
        const int ln  = rem & 63;
        const int tv  = nt * 16 + (ln & 15);              // < 176 always
        const int c0  = kb * 32 + (ln >> 4) * 8;
        ushort tmp[8];
        #pragma unroll
        for (int j = 0; j < 8; ++j) tmp[j] = z_lds[(size_t)(c0 + j) * ZROW + tv];
        *reinterpret_cast<uint4*>(&zbf[(size_t)it * 8]) = *reinterpret_cast<const uint4*>(tmp);
    }
    __syncthreads();

    // ---- Phase B: out = relu(Wd @ z + bd); wave owns 32 o's, streams nt ----
    {
        const int o0 = wave * 32;
        float bdv[2][4];
        #pragma unroll
        for (int mt = 0; mt < 2; ++mt)
            #pragma unroll
            for (int r = 0; r < 4; ++r)
                bdv[mt][r] = bd[o0 + mt * 16 + hi * 4 + r];
        bf16x8 aw[2][2];   // [kb][mt], loaded once (L1-resident)
        #pragma unroll
        for (int kb = 0; kb < 2; ++kb)
            #pragma unroll
            for (int mt = 0; mt < 2; ++mt)
                aw[kb][mt] = *reinterpret_cast<const bf16x8*>(
                    &WdB[(size_t)(o0 + mt * 16 + lo) * CIN + kb * 32 + hi * 8]);

        for (int nt = 0; nt < 11; ++nt) {
            f32x4 acc2[2];
            #pragma unroll
            for (int mt = 0; mt < 2; ++mt)
                #pragma unroll
                for (int r = 0; r < 4; ++r) acc2[mt][r] = bdv[mt][r];
            #pragma unroll
            for (int kb = 0; kb < 2; ++kb) {
                bf16x8 bfr = *reinterpret_cast<const bf16x8*>(&zbf[((kb * 11 + nt) * 64 + lane) * 8]);
                #pragma unroll
                for (int mt = 0; mt < 2; ++mt)
                    acc2[mt] = __builtin_amdgcn_mfma_f32_16x16x32_bf16(aw[kb][mt], bfr, acc2[mt], 0, 0, 0);
            }
            const int col = nt * 16 + lo;                 // < 176 always
            #pragma unroll
            for (int mt = 0; mt < 2; ++mt) {
                #pragma unroll
                for (int r = 0; r < 4; ++r) {
                    const int o = o0 + mt * 16 + hi * 4 + r;
                    out[((size_t)(n * COUT + o)) * (TT * VV) + (size_t)tq * ZROW + col]
                        = fmaxf(acc2[mt][r], 0.f);
                }
            }
        }
    }
}

// ===================== Fallback: verified R1 monolithic kernel =====================
__global__ __launch_bounds__(256, 4) void agcn_fused(
    const float* __restrict__ x, const float* __restrict__ A,
    const float* __restrict__ Wa, const float* __restrict__ ba,
    const float* __restrict__ Wb, const float* __restrict__ bb,
    const float* __restrict__ Wd, const float* __restrict__ bd,
    float* __restrict__ out)
{
    const int t   = blockIdx.x;
    const int n   = blockIdx.y;
    const int tid = threadIdx.x;
    __shared__ float smem[7424];
    float* xs   = smem;
    float* A1s  = smem + 1536;
    float* A2s  = smem + 3072;
    float* Ssf  = smem + 4608;
    float* Psf  = smem + 5136;
    float* outs = smem;
    float* zs   = smem + 5888;

    for (int f = tid; f < CIN * VV; f += 256) {
        int c = f / VV, v = f - c * VV;
        xs[c * PAD + v] = x[(((size_t)n * CIN + c) * TT + t) * VV + v];
    }
    {
        const float* Ag = A + (((size_t)n * TT + t) * VV) * VV;
        for (int f = tid; f < VV * VV; f += 256) {
            int u = f / VV, v = f - u * VV;
            Psf[u * PAD + v] = Ag[f] + 1e-6f;
        }
    }
    __syncthreads();
    {
        const int r  = tid & 63;
        const int q  = tid >> 6;
        const int us = (q * VV) >> 2;
        const int ue = ((q + 1) * VV) >> 2;
        const float* War = Wa + r * CIN;
        const float* Wbr = Wb + r * CIN;
        float acc1[6], acc2[6];
        const float b1 = ba[r], b2 = bb[r];
        #pragma unroll
        for (int u = 0; u < 6; ++u) { acc1[u] = b1; acc2[u] = b2; }
        for (int c = 0; c < CIN; c += 4) {
            float4 wa4 = *reinterpret_cast<const float4*>(War + c);
            float4 wb4 = *reinterpret_cast<const float4*>(Wbr + c);
            #pragma unroll
            for (int u = 0; u < 6; ++u) {
                float x0 = xs[(c + 0) * PAD + us + u];
                float x1 = xs[(c + 1) * PAD + us + u];
                float x2 = xs[(c + 2) * PAD + us + u];
                float x3 = xs[(c + 3) * PAD + us + u];
                acc1[u] += wa4.x * x0 + wa4.y * x1 + wa4.z * x2 + wa4.w * x3;
                acc2[u] += wb4.x * x0 + wb4.y * x1 + wb4.z * x2 + wb4.w * x3;
            }
        }
        #pragma unroll
        for (int u = 0; u < 6; ++u) {
            if (us + u < ue) {
                A1s[r * PAD + us + u] = acc1[u];
                A2s[r * PAD + us + u] = acc2[u];
            }
        }
    }
    __syncthreads();
    for (int f = tid; f < VV * VV; f += 256) {
        int u = f / VV, v = f - u * VV;
        float s = 0.f;
        for (int i = 0; i < CIN; ++i)
            s += A1s[i * PAD + u] * A2s[i * PAD + v];
        Ssf[u * PAD + v] = s * (1.0f / 64.0f);
    }
    __syncthreads();
    if (tid < VV) {
        const int v = tid;
        float m = -1e30f;
        #pragma unroll
        for (int u = 0; u < VV; ++u) m = fmaxf(m, Ssf[u * PAD + v]);
        float sum = 0.f;
        #pragma unroll
        for (int u = 0; u < VV; ++u) sum += __expf(Ssf[u * PAD + v] - m);
        const float inv = 1.0f / sum;
        #pragma unroll
        for (int u = 0; u < VV; ++u)
            Psf[u * PAD + v] += __expf(Ssf[u * PAD + v] - m) * inv;
    }
    __syncthreads();
    for (int f = tid; f < CIN * VV; f += 256) {
        int c = f / VV, u = f - c * VV;
        float s = 0.f;
        #pragma unroll
        for (int w = 0; w < VV; ++w)
            s += Psf[u * PAD + w] * xs[c * PAD + w];
        zs[c * PAD + u] = s;
    }
    __syncthreads();
    {
        const int o = tid;
        const float* Wr = Wd + o * CIN;
        float acc[VV];
        const float b = bd[o];
        #pragma unroll
        for (int u = 0; u < VV; ++u) acc[u] = b;
        for (int c = 0; c < CIN; c += 4) {
            float4 w4 = *reinterpret_cast<const float4*>(Wr + c);
            #pragma unroll
            for (int cc = 0; cc < 4; ++cc) {
                const float w = (cc == 0) ? w4.x : (cc == 1) ? w4.y : (cc == 2) ? w4.z : w4.w;
                const float* zr = zs + (c + cc) * PAD;
                #pragma unroll
                for (int uq = 0; uq < 5; ++uq) {
                    float4 zq = *reinterpret_cast<const float4*>(zr + uq * 4);
                    acc[uq * 4 + 0] += w * zq.x;
                    acc[uq * 4 + 1] += w * zq.y;
                    acc[uq * 4 + 2] += w * zq.z;
                    acc[uq * 4 + 3] += w * zq.w;
                }
                float2 zt = *reinterpret_cast<const float2*>(zr + 20);
                acc[20] += w * zt.x;
                acc[21] += w * zt.y;
            }
        }
        #pragma unroll
        for (int u = 0; u < VV; ++u)
            outs[o * OPAD + u] = fmaxf(acc[u], 0.f);
    }
    __syncthreads();
    {
        const size_t obase = (size_t)n * COUT * TT * VV + (size_t)t * VV;
        for (int f = tid; f < COUT * VV; f += 256) {
            int o = f / VV, u = f - o * VV;
            out[obase + (size_t)o * (TT * VV) + u] = outs[o * OPAD + u];
        }
    }
}

extern "C" void kernel_launch(void* const* d_in, const int* in_sizes, int n_in,
                              void* d_out, int out_size, void* d_ws, size_t ws_size,
                              hipStream_t stream) {
    const float* x  = (const float*)d_in[0];
    const float* A  = (const float*)d_in[1];
    const float* Wa = (const float*)d_in[2];
    const float* ba = (const float*)d_in[3];
    const float* Wb = (const float*)d_in[4];
    const float* bb = (const float*)d_in[5];
    const float* Wd = (const float*)d_in[6];
    const float* bd = (const float*)d_in[7];
    float* outp     = (float*)d_out;

    const size_t wab_bytes = (size_t)CIN * CIN * sizeof(ushort);    // 8 KB each
    const size_t wdb_bytes = (size_t)COUT * CIN * sizeof(ushort);   // 32 KB

    if (ws_size >= 2 * wab_bytes + wdb_bytes) {
        ushort* wab = (ushort*)d_ws;
        ushort* wbb = (ushort*)((char*)d_ws + wab_bytes);
        ushort* wdb = (ushort*)((char*)d_ws + 2 * wab_bytes);
        const int prep_items = 2 * CIN * CIN + COUT * CIN;   // 24576
        w_to_bf16<<<(prep_items + 255) / 256, 256, 0, stream>>>(Wa, Wb, Wd, wab, wbb, wdb);
        dim3 g(NTB, NB);
        agcn_fused_mfma<<<g, 512, 0, stream>>>(x, A, wab, ba, wbb, bb, wdb, bd, outp);
    } else {
        dim3 grid(TT, NB);
        agcn_fused<<<grid, 256, 0, stream>>>(x, A, Wa, ba, Wb, bb, Wd, bd, outp);
    }
}